// Round 3
// baseline (1839.199 us; speedup 1.0000x reference)
//
#include <hip/hip_runtime.h>
#include <math.h>

#define NFEAT 128
#define NHID  24
#define NCLS  16
#define BSH   6                 // bucket shift: 64 nodes per bucket
#define BN    64                // nodes per bucket

// ---------------------------------------------------------------------------
// K1: bucket histogram (global atomics, 1563 counters)
__global__ void bhist_kernel(const int* __restrict__ ei, int* __restrict__ bhist, int E) {
    int e = blockIdx.x * blockDim.x + threadIdx.x;
    if (e < E) atomicAdd(&bhist[ei[e] >> BSH], 1);
}

// K2a/b/c: 3-level exclusive scan over NB bucket counts -> bbase, bcur
__global__ void scan1_kernel(const int* __restrict__ cnt, int* __restrict__ rowst,
                             int* __restrict__ bsum, int N) {
    __shared__ int s[256];
    int t = threadIdx.x;
    int i = blockIdx.x * 256 + t;
    int v = (i < N) ? cnt[i] : 0;
    s[t] = v;
    __syncthreads();
    for (int o = 1; o < 256; o <<= 1) {
        int x = (t >= o) ? s[t - o] : 0;
        __syncthreads();
        s[t] += x;
        __syncthreads();
    }
    if (i < N) rowst[i] = s[t] - v;
    if (t == 255) bsum[blockIdx.x] = s[255];
}
__global__ void scan2_kernel(int* __restrict__ bsum, int nb) {
    __shared__ int s[512];
    int t = threadIdx.x;
    int v = (t < nb) ? bsum[t] : 0;
    s[t] = v;
    __syncthreads();
    for (int o = 1; o < 512; o <<= 1) {
        int x = (t >= o) ? s[t - o] : 0;
        __syncthreads();
        s[t] += x;
        __syncthreads();
    }
    if (t < nb) bsum[t] = s[t] - v;
}
__global__ void scan3_kernel(int* __restrict__ rowst, int* __restrict__ cursor,
                             const int* __restrict__ bsum, int N) {
    int i = blockIdx.x * 256 + threadIdx.x;
    if (i < N) {
        int r = rowst[i] + bsum[blockIdx.x];
        rowst[i] = r;
        cursor[i] = r;
    }
}

// K3: partition edges into bucket-contiguous packed entries (local_dst<<17 | src)
__global__ void part_kernel(const int* __restrict__ ei, int* __restrict__ bcur,
                            int* __restrict__ part, int E) {
    int e = blockIdx.x * blockDim.x + threadIdx.x;
    if (e < E) {
        int dst = ei[e];
        int src = ei[E + e];
        int b = dst >> BSH;
        int p = atomicAdd(&bcur[b], 1);
        part[p] = ((dst & (BN - 1)) << 17) | src;
    }
}

// K4: per-bucket degree count -> dinv = rsqrt(deg+1)
__global__ void __launch_bounds__(256) degv_kernel(const int* __restrict__ part,
                                                   const int* __restrict__ bbase,
                                                   float* __restrict__ dinv,
                                                   int NB, int E, int N) {
    __shared__ int lcnt[BN];
    int b = blockIdx.x;
    if (threadIdx.x < BN) lcnt[threadIdx.x] = 0;
    __syncthreads();
    int st = bbase[b];
    int en = (b == NB - 1) ? E : bbase[b + 1];
    for (int e = st + threadIdx.x; e < en; e += 256)
        atomicAdd(&lcnt[part[e] >> 17], 1);
    __syncthreads();
    if (threadIdx.x < BN) {
        int node = (b << BSH) + threadIdx.x;
        if (node < N) dinv[node] = rsqrtf((float)lcnt[threadIdx.x] + 1.0f);
    }
}

// K5: h1s = dinv[row] * (x @ W1); W1 staged in LDS (12 KB)
__global__ void __launch_bounds__(256) gemm1_kernel(const float* __restrict__ x,
                                                    const float* __restrict__ W1,
                                                    const float* __restrict__ dinv,
                                                    float* __restrict__ h1s, int N) {
    __shared__ float w[NFEAT * NHID];
    for (int i = threadIdx.x; i < NFEAT * NHID; i += blockDim.x) w[i] = W1[i];
    __syncthreads();
    int row = blockIdx.x * blockDim.x + threadIdx.x;
    if (row >= N) return;
    float acc[NHID];
#pragma unroll
    for (int j = 0; j < NHID; j++) acc[j] = 0.0f;
    const float4* xr = (const float4*)(x + (size_t)row * NFEAT);
    for (int k4 = 0; k4 < NFEAT / 4; k4++) {
        float4 v = xr[k4];
        const float* wr = &w[k4 * 4 * NHID];
#pragma unroll
        for (int j = 0; j < NHID; j++) acc[j] += v.x * wr[j];
#pragma unroll
        for (int j = 0; j < NHID; j++) acc[j] += v.y * wr[NHID + j];
#pragma unroll
        for (int j = 0; j < NHID; j++) acc[j] += v.z * wr[2 * NHID + j];
#pragma unroll
        for (int j = 0; j < NHID; j++) acc[j] += v.w * wr[3 * NHID + j];
    }
    float di = dinv[row];
    float* o = h1s + (size_t)row * NHID;
#pragma unroll
    for (int j = 0; j < NHID; j++) o[j] = di * acc[j];
}

// K6: layer-1 aggregation: one workgroup per bucket, 64-node LDS accumulator.
//     192 threads = 8 edge-slots x 24 feature lanes; LDS float atomics.
//     Epilogue: hrelu = relu(dinv*(acc + h1s_self) + b1)
__global__ void __launch_bounds__(192) agg1_kernel(const int* __restrict__ part,
                                                   const int* __restrict__ bbase,
                                                   const float* __restrict__ h1s,
                                                   const float* __restrict__ dinv,
                                                   const float* __restrict__ b1,
                                                   float* __restrict__ hrelu,
                                                   int NB, int E, int N) {
    __shared__ float acc[BN * NHID];   // 6 KB
    int b = blockIdx.x;
    for (int i = threadIdx.x; i < BN * NHID; i += 192) acc[i] = 0.0f;
    __syncthreads();
    int st = bbase[b];
    int en = (b == NB - 1) ? E : bbase[b + 1];
    int slot = threadIdx.x / NHID;      // 0..7
    int f = threadIdx.x - slot * NHID;  // 0..23
    int e = st + slot;
    for (; e + 24 < en; e += 32) {      // 4-way unrolled, stride 8 slots
        int e0 = part[e], e1 = part[e + 8], e2 = part[e + 16], e3 = part[e + 24];
        float v0 = h1s[(e0 & 0x1FFFF) * NHID + f];
        float v1 = h1s[(e1 & 0x1FFFF) * NHID + f];
        float v2 = h1s[(e2 & 0x1FFFF) * NHID + f];
        float v3 = h1s[(e3 & 0x1FFFF) * NHID + f];
        atomicAdd(&acc[(e0 >> 17) * NHID + f], v0);
        atomicAdd(&acc[(e1 >> 17) * NHID + f], v1);
        atomicAdd(&acc[(e2 >> 17) * NHID + f], v2);
        atomicAdd(&acc[(e3 >> 17) * NHID + f], v3);
    }
    for (; e < en; e += 8) {
        int ent = part[e];
        atomicAdd(&acc[(ent >> 17) * NHID + f], h1s[(ent & 0x1FFFF) * NHID + f]);
    }
    __syncthreads();
    float bf = b1[f];
    for (int ln = slot; ln < BN; ln += 8) {
        int node = (b << BSH) + ln;
        if (node >= N) break;
        float di = dinv[node];
        float v = di * (acc[ln * NHID + f] + h1s[node * NHID + f]) + bf;
        hrelu[node * NHID + f] = fmaxf(v, 0.0f);
    }
}

// K7: h2s = dinv[row] * (hrelu @ W2)   (24 -> 16, W2 in LDS)
__global__ void __launch_bounds__(256) fuse2_kernel(const float* __restrict__ hrelu,
                                                    const float* __restrict__ dinv,
                                                    const float* __restrict__ W2,
                                                    float* __restrict__ h2s, int N) {
    __shared__ float w[NHID * NCLS];
    for (int i = threadIdx.x; i < NHID * NCLS; i += blockDim.x) w[i] = W2[i];
    __syncthreads();
    int row = blockIdx.x * blockDim.x + threadIdx.x;
    if (row >= N) return;
    float hr[NHID];
    const float4* h4 = (const float4*)(hrelu + (size_t)row * NHID);
#pragma unroll
    for (int q = 0; q < NHID / 4; q++) {
        float4 hv = h4[q];
        hr[4 * q + 0] = hv.x;
        hr[4 * q + 1] = hv.y;
        hr[4 * q + 2] = hv.z;
        hr[4 * q + 3] = hv.w;
    }
    float acc[NCLS];
#pragma unroll
    for (int j = 0; j < NCLS; j++) acc[j] = 0.0f;
#pragma unroll
    for (int k = 0; k < NHID; k++) {
#pragma unroll
        for (int j = 0; j < NCLS; j++) acc[j] += hr[k] * w[k * NCLS + j];
    }
    float di = dinv[row];
    float* o = h2s + (size_t)row * NCLS;
#pragma unroll
    for (int j = 0; j < NCLS; j++) o[j] = di * acc[j];
}

// K8: layer-2 aggregation + self-loop + b2 + log_softmax.
//     256 threads = 16 edge-slots x 16 lanes; 64-node LDS accumulator.
__global__ void __launch_bounds__(256) agg2_kernel(const int* __restrict__ part,
                                                   const int* __restrict__ bbase,
                                                   const float* __restrict__ h2s,
                                                   const float* __restrict__ dinv,
                                                   const float* __restrict__ b2,
                                                   float* __restrict__ out,
                                                   int NB, int E, int N) {
    __shared__ float acc[BN * NCLS];   // 4 KB
    int b = blockIdx.x;
    for (int i = threadIdx.x; i < BN * NCLS; i += 256) acc[i] = 0.0f;
    __syncthreads();
    int st = bbase[b];
    int en = (b == NB - 1) ? E : bbase[b + 1];
    int slot = threadIdx.x >> 4;        // 0..15
    int f = threadIdx.x & 15;
    int e = st + slot;
    for (; e + 48 < en; e += 64) {      // 4-way unrolled, stride 16 slots
        int e0 = part[e], e1 = part[e + 16], e2 = part[e + 32], e3 = part[e + 48];
        float v0 = h2s[(e0 & 0x1FFFF) * NCLS + f];
        float v1 = h2s[(e1 & 0x1FFFF) * NCLS + f];
        float v2 = h2s[(e2 & 0x1FFFF) * NCLS + f];
        float v3 = h2s[(e3 & 0x1FFFF) * NCLS + f];
        atomicAdd(&acc[(e0 >> 17) * NCLS + f], v0);
        atomicAdd(&acc[(e1 >> 17) * NCLS + f], v1);
        atomicAdd(&acc[(e2 >> 17) * NCLS + f], v2);
        atomicAdd(&acc[(e3 >> 17) * NCLS + f], v3);
    }
    for (; e < en; e += 16) {
        int ent = part[e];
        atomicAdd(&acc[(ent >> 17) * NCLS + f], h2s[(ent & 0x1FFFF) * NCLS + f]);
    }
    __syncthreads();
    float bf = b2[f];
    for (int ln = slot; ln < BN; ln += 16) {
        int node = (b << BSH) + ln;
        if (node >= N) break;           // uniform across the 16-lane group
        float di = dinv[node];
        float l = di * (acc[ln * NCLS + f] + h2s[node * NCLS + f]) + bf;
        float m = l;
#pragma unroll
        for (int o = 1; o < 16; o <<= 1) m = fmaxf(m, __shfl_xor(m, o, 16));
        float ex = expf(l - m);
        float ssum = ex;
#pragma unroll
        for (int o = 1; o < 16; o <<= 1) ssum += __shfl_xor(ssum, o, 16);
        out[node * NCLS + f] = l - (logf(ssum) + m);
    }
}

extern "C" void kernel_launch(void* const* d_in, const int* in_sizes, int n_in,
                              void* d_out, int out_size, void* d_ws, size_t ws_size,
                              hipStream_t stream) {
    const float* x  = (const float*)d_in[0];
    const int*   ei = (const int*)d_in[1];
    const float* W1 = (const float*)d_in[2];
    const float* b1 = (const float*)d_in[3];
    const float* W2 = (const float*)d_in[4];
    const float* b2 = (const float*)d_in[5];
    float* out = (float*)d_out;

    const int N = in_sizes[0] / NFEAT;   // 100000
    const int E = in_sizes[1] / 2;       // 3200000
    const int NB = (N + BN - 1) >> BSH;  // 1563 buckets

    // workspace: [bhist NB][bbase NB][bcur NB][bsum 512][part E] ints,
    // then [dinv N][h1s 24N][hrelu 24N] floats; h2s aliases h1s.
    int* bhist = (int*)d_ws;
    int* bbase = bhist + NB;
    int* bcur  = bbase + NB;
    int* bsum  = bcur + NB;
    int* part  = bsum + 512;
    float* dinv  = (float*)(part + E);
    float* h1s   = dinv + N;
    float* hrelu = h1s + (size_t)N * NHID;
    float* h2s   = h1s;   // h1s dead after agg1

    hipMemsetAsync(bhist, 0, (size_t)NB * sizeof(int), stream);

    const int B = 256;
    const int nbs = (NB + B - 1) / B;    // 7 scan blocks
    bhist_kernel<<<(E + B - 1) / B, B, 0, stream>>>(ei, bhist, E);
    scan1_kernel<<<nbs, B, 0, stream>>>(bhist, bbase, bsum, NB);
    scan2_kernel<<<1, 512, 0, stream>>>(bsum, nbs);
    scan3_kernel<<<nbs, B, 0, stream>>>(bbase, bcur, bsum, NB);
    part_kernel<<<(E + B - 1) / B, B, 0, stream>>>(ei, bcur, part, E);
    degv_kernel<<<NB, B, 0, stream>>>(part, bbase, dinv, NB, E, N);
    gemm1_kernel<<<(N + B - 1) / B, B, 0, stream>>>(x, W1, dinv, h1s, N);
    agg1_kernel<<<NB, 192, 0, stream>>>(part, bbase, h1s, dinv, b1, hrelu, NB, E, N);
    fuse2_kernel<<<(N + B - 1) / B, B, 0, stream>>>(hrelu, dinv, W2, h2s, N);
    agg2_kernel<<<NB, B, 0, stream>>>(part, bbase, h2s, dinv, b2, out, NB, E, N);
}

// Round 4
// 376.672 us; speedup vs baseline: 4.8828x; 4.8828x over previous
//
#include <hip/hip_runtime.h>
#include <math.h>

#define NFEAT 128
#define NHID  24
#define NCLS  16
#define NBSH  10                // 1024 nodes per coarse bucket
#define BKN   1024
#define TILE  8192              // edges staged per partition block
#define PT    256               // partition block threads
#define EPT   (TILE / PT)       // 32 edges per thread

// ---------------------------------------------------------------------------
// K1: coarse bucket histogram — LDS hist per block, 98 global atomics per block
__global__ void __launch_bounds__(256) bhist_kernel(const int* __restrict__ ei,
                                                    int* __restrict__ bhist,
                                                    int E, int NBUCK) {
    __shared__ int lh[128];
    if (threadIdx.x < 128) lh[threadIdx.x] = 0;
    __syncthreads();
    int stride = gridDim.x * blockDim.x;
    for (int e = blockIdx.x * blockDim.x + threadIdx.x; e < E; e += stride)
        atomicAdd(&lh[ei[e] >> NBSH], 1);
    __syncthreads();
    if (threadIdx.x < NBUCK && lh[threadIdx.x])
        atomicAdd(&bhist[threadIdx.x], lh[threadIdx.x]);
}

// K2: exclusive scan of 98 bucket counts -> bbase (with sentinel), gcur
__global__ void bscan_kernel(const int* __restrict__ bhist, int* __restrict__ bbase,
                             int* __restrict__ gcur, int NBUCK, int E) {
    __shared__ int s[128];
    int t = threadIdx.x;
    int v = (t < NBUCK) ? bhist[t] : 0;
    s[t] = v;
    __syncthreads();
    for (int o = 1; o < 128; o <<= 1) {
        int x = (t >= o) ? s[t - o] : 0;
        __syncthreads();
        s[t] += x;
        __syncthreads();
    }
    if (t < NBUCK) {
        int ex = s[t] - v;
        bbase[t] = ex;
        gcur[t] = ex;
    }
    if (t == 0) bbase[NBUCK] = E;
}

// K3: LDS-staged partition into coarse buckets; coalesced run copy-out.
//     part entry = (local_dst<<17) | src   (local_dst<1024, src<131072)
__global__ void __launch_bounds__(256) part1_kernel(const int* __restrict__ ei,
                                                    int* __restrict__ gcur,
                                                    int* __restrict__ part, int E) {
    __shared__ int stage[TILE];   // 32 KB
    __shared__ int lh[128];       // hist, then cursor
    __shared__ int sc[128];       // scan temp
    __shared__ int lofs[129];     // exclusive offsets for binary search
    __shared__ int gbase[128];
    int t = threadIdx.x;
    int e0 = blockIdx.x * TILE;
    int cnt_tile = min(TILE, E - e0);
    if (t < 128) lh[t] = 0;
    __syncthreads();
    int pk[EPT];
    unsigned char bk[EPT];
    int m = 0;
    for (int i = t; i < cnt_tile; i += PT) {
        int dst = ei[e0 + i];
        int src = ei[E + e0 + i];
        int b = dst >> NBSH;
        pk[m] = ((dst & (BKN - 1)) << 17) | src;
        bk[m] = (unsigned char)b;
        m++;
        atomicAdd(&lh[b], 1);
    }
    __syncthreads();
    if (t < 128) sc[t] = lh[t];
    __syncthreads();
    for (int o = 1; o < 128; o <<= 1) {
        int v = (t < 128 && t >= o) ? sc[t - o] : 0;
        __syncthreads();
        if (t < 128) sc[t] += v;
        __syncthreads();
    }
    if (t < 128) {
        int cb = lh[t];
        int ex = sc[t] - cb;
        lofs[t] = ex;
        gbase[t] = cb ? atomicAdd(&gcur[t], cb) : 0;
        lh[t] = ex;   // becomes LDS cursor
    }
    if (t == 0) lofs[128] = cnt_tile;
    __syncthreads();
    for (int i = 0; i < m; i++) {
        int p = atomicAdd(&lh[bk[i]], 1);
        stage[p] = pk[i];
    }
    __syncthreads();
    // coalesced copy-out: find bucket of staged slot i via binary search
    for (int i = t; i < cnt_tile; i += PT) {
        int lo = 0, hi = 127;
        while (lo < hi) {
            int mid = (lo + hi + 1) >> 1;
            if (lofs[mid] <= i) lo = mid; else hi = mid - 1;
        }
        part[gbase[lo] + (i - lofs[lo])] = stage[i];
    }
}

// K4: per-bucket CSR build: per-node hist -> scan -> rowst/dinv -> scatter src.
//     One 1024-thread block per bucket; all writes confined to the bucket window.
__global__ void __launch_bounds__(1024) csr_kernel(const int* __restrict__ part,
                                                   const int* __restrict__ bbase,
                                                   int* __restrict__ csr,
                                                   int* __restrict__ rowst,
                                                   float* __restrict__ dinv,
                                                   int NBUCK, int N, int E) {
    __shared__ int h[1024];
    __shared__ int cur[1024];
    int b = blockIdx.x, t = threadIdx.x;
    int st = bbase[b], en = bbase[b + 1];
    h[t] = 0;
    __syncthreads();
    for (int e = st + t; e < en; e += 1024)
        atomicAdd(&h[part[e] >> 17], 1);
    __syncthreads();
    int myc = h[t];
    for (int o = 1; o < 1024; o <<= 1) {   // inclusive scan
        int v = (t >= o) ? h[t - o] : 0;
        __syncthreads();
        h[t] += v;
        __syncthreads();
    }
    int ex = h[t] - myc;
    int node = (b << NBSH) + t;
    if (node < N) {
        rowst[node] = st + ex;
        dinv[node] = rsqrtf((float)myc + 1.0f);
    }
    if (b == NBUCK - 1 && t == 0) rowst[N] = E;
    cur[t] = ex;
    __syncthreads();
    for (int e = st + t; e < en; e += 1024) {
        int ent = part[e];
        int p = atomicAdd(&cur[ent >> 17], 1);
        csr[st + p] = ent & 0x1FFFF;
    }
}

// K5: h1s = dinv[row] * (x @ W1); W1 staged in LDS (12 KB)
__global__ void __launch_bounds__(256) gemm1_kernel(const float* __restrict__ x,
                                                    const float* __restrict__ W1,
                                                    const float* __restrict__ dinv,
                                                    float* __restrict__ h1s, int N) {
    __shared__ float w[NFEAT * NHID];
    for (int i = threadIdx.x; i < NFEAT * NHID; i += blockDim.x) w[i] = W1[i];
    __syncthreads();
    int row = blockIdx.x * blockDim.x + threadIdx.x;
    if (row >= N) return;
    float acc[NHID];
#pragma unroll
    for (int j = 0; j < NHID; j++) acc[j] = 0.0f;
    const float4* xr = (const float4*)(x + (size_t)row * NFEAT);
    for (int k4 = 0; k4 < NFEAT / 4; k4++) {
        float4 v = xr[k4];
        const float* wr = &w[k4 * 4 * NHID];
#pragma unroll
        for (int j = 0; j < NHID; j++) acc[j] += v.x * wr[j];
#pragma unroll
        for (int j = 0; j < NHID; j++) acc[j] += v.y * wr[NHID + j];
#pragma unroll
        for (int j = 0; j < NHID; j++) acc[j] += v.z * wr[2 * NHID + j];
#pragma unroll
        for (int j = 0; j < NHID; j++) acc[j] += v.w * wr[3 * NHID + j];
    }
    float di = dinv[row];
    float* o = h1s + (size_t)row * NHID;
#pragma unroll
    for (int j = 0; j < NHID; j++) o[j] = di * acc[j];
}

// K6: layer-1 pull aggregation over CSR + fused self-loop/bias/relu
__global__ void __launch_bounds__(192) agg1_kernel(const int* __restrict__ csr,
                                                   const int* __restrict__ rowst,
                                                   const float* __restrict__ h1s,
                                                   const float* __restrict__ dinv,
                                                   const float* __restrict__ b1,
                                                   float* __restrict__ hrelu, int N) {
    int g = threadIdx.x / NHID;
    int f = threadIdx.x - g * NHID;
    int node = blockIdx.x * 8 + g;
    if (node >= N) return;
    int st = rowst[node];
    int dg = rowst[node + 1] - st;
    float a0 = 0.f, a1 = 0.f, a2 = 0.f, a3 = 0.f;
    int e = 0;
    for (; e + 4 <= dg; e += 4) {
        int s0 = csr[st + e];
        int s1 = csr[st + e + 1];
        int s2 = csr[st + e + 2];
        int s3 = csr[st + e + 3];
        a0 += h1s[s0 * NHID + f];
        a1 += h1s[s1 * NHID + f];
        a2 += h1s[s2 * NHID + f];
        a3 += h1s[s3 * NHID + f];
    }
    for (; e < dg; e++) a0 += h1s[csr[st + e] * NHID + f];
    float sum = (a0 + a1) + (a2 + a3);
    float v = dinv[node] * (sum + h1s[node * NHID + f]) + b1[f];
    hrelu[node * NHID + f] = fmaxf(v, 0.0f);
}

// K7: h2s = dinv[row] * (hrelu @ W2)
__global__ void __launch_bounds__(256) fuse2_kernel(const float* __restrict__ hrelu,
                                                    const float* __restrict__ dinv,
                                                    const float* __restrict__ W2,
                                                    float* __restrict__ h2s, int N) {
    __shared__ float w[NHID * NCLS];
    for (int i = threadIdx.x; i < NHID * NCLS; i += blockDim.x) w[i] = W2[i];
    __syncthreads();
    int row = blockIdx.x * blockDim.x + threadIdx.x;
    if (row >= N) return;
    float hr[NHID];
    const float4* h4 = (const float4*)(hrelu + (size_t)row * NHID);
#pragma unroll
    for (int q = 0; q < NHID / 4; q++) {
        float4 hv = h4[q];
        hr[4 * q + 0] = hv.x;
        hr[4 * q + 1] = hv.y;
        hr[4 * q + 2] = hv.z;
        hr[4 * q + 3] = hv.w;
    }
    float acc[NCLS];
#pragma unroll
    for (int j = 0; j < NCLS; j++) acc[j] = 0.0f;
#pragma unroll
    for (int k = 0; k < NHID; k++) {
#pragma unroll
        for (int j = 0; j < NCLS; j++) acc[j] += hr[k] * w[k * NCLS + j];
    }
    float di = dinv[row];
    float* o = h2s + (size_t)row * NCLS;
#pragma unroll
    for (int j = 0; j < NCLS; j++) o[j] = di * acc[j];
}

// K8: layer-2 pull aggregation + self-loop + b2 + log_softmax
__global__ void __launch_bounds__(256) agg2_kernel(const int* __restrict__ csr,
                                                   const int* __restrict__ rowst,
                                                   const float* __restrict__ h2s,
                                                   const float* __restrict__ dinv,
                                                   const float* __restrict__ b2,
                                                   float* __restrict__ out, int N) {
    int g = threadIdx.x >> 4;
    int f = threadIdx.x & 15;
    int node = blockIdx.x * 16 + g;
    if (node >= N) return;
    int st = rowst[node];
    int dg = rowst[node + 1] - st;
    float a0 = 0.f, a1 = 0.f, a2 = 0.f, a3 = 0.f;
    int e = 0;
    for (; e + 4 <= dg; e += 4) {
        int s0 = csr[st + e];
        int s1 = csr[st + e + 1];
        int s2 = csr[st + e + 2];
        int s3 = csr[st + e + 3];
        a0 += h2s[s0 * NCLS + f];
        a1 += h2s[s1 * NCLS + f];
        a2 += h2s[s2 * NCLS + f];
        a3 += h2s[s3 * NCLS + f];
    }
    for (; e < dg; e++) a0 += h2s[csr[st + e] * NCLS + f];
    float sum = (a0 + a1) + (a2 + a3);
    float l = dinv[node] * (sum + h2s[node * NCLS + f]) + b2[f];
    float m = l;
#pragma unroll
    for (int o = 1; o < 16; o <<= 1) m = fmaxf(m, __shfl_xor(m, o, 16));
    float ex = expf(l - m);
    float ssum = ex;
#pragma unroll
    for (int o = 1; o < 16; o <<= 1) ssum += __shfl_xor(ssum, o, 16);
    out[node * NCLS + f] = l - (logf(ssum) + m);
}

extern "C" void kernel_launch(void* const* d_in, const int* in_sizes, int n_in,
                              void* d_out, int out_size, void* d_ws, size_t ws_size,
                              hipStream_t stream) {
    const float* x  = (const float*)d_in[0];
    const int*   ei = (const int*)d_in[1];
    const float* W1 = (const float*)d_in[2];
    const float* b1 = (const float*)d_in[3];
    const float* W2 = (const float*)d_in[4];
    const float* b2 = (const float*)d_in[5];
    float* out = (float*)d_out;

    const int N = in_sizes[0] / NFEAT;        // 100000
    const int E = in_sizes[1] / 2;            // 3200000
    const int NBUCK = (N + BKN - 1) >> NBSH;  // 98

    // workspace (4-byte units):
    // [bhist 128][bbase 129][gcur 128][rowst N+1][csr E][dinv N][h1s 24N]
    // [union: part E  /  hrelu 24N]   (part dead after csr_kernel; hrelu written in agg1)
    int* bhist = (int*)d_ws;
    int* bbase = bhist + 128;
    int* gcur  = bbase + 129;
    int* rowst = gcur + 128;
    int* csr   = rowst + (N + 1);
    float* dinv = (float*)(csr + E);
    float* h1s  = dinv + N;
    int*   part  = (int*)(h1s + (size_t)N * NHID);
    float* hrelu = (float*)part;
    float* h2s   = h1s;   // h1s dead after agg1

    hipMemsetAsync(bhist, 0, 128 * sizeof(int), stream);

    const int B = 256;
    bhist_kernel<<<512, B, 0, stream>>>(ei, bhist, E, NBUCK);
    bscan_kernel<<<1, 128, 0, stream>>>(bhist, bbase, gcur, NBUCK, E);
    part1_kernel<<<(E + TILE - 1) / TILE, PT, 0, stream>>>(ei, gcur, part, E);
    csr_kernel<<<NBUCK, 1024, 0, stream>>>(part, bbase, csr, rowst, dinv, NBUCK, N, E);
    gemm1_kernel<<<(N + B - 1) / B, B, 0, stream>>>(x, W1, dinv, h1s, N);
    agg1_kernel<<<(N + 7) / 8, 192, 0, stream>>>(csr, rowst, h1s, dinv, b1, hrelu, N);
    fuse2_kernel<<<(N + B - 1) / B, B, 0, stream>>>(hrelu, dinv, W2, h2s, N);
    agg2_kernel<<<(N + 15) / 16, B, 0, stream>>>(csr, rowst, h2s, dinv, b2, out, N);
}

// Round 5
// 299.555 us; speedup vs baseline: 6.1398x; 1.2574x over previous
//
#include <hip/hip_runtime.h>
#include <math.h>

#define NFEAT 128
#define NHID  24
#define NCLS  16
#define H1STR 32                // h1s bf16 row stride (64 B, line-aligned)
#define NBSH  8                 // 256 nodes per bucket
#define BKN   256
#define TILE  8192              // edges per partition tile
#define PT    512               // partition block threads

typedef unsigned short ushort_t;

__device__ __forceinline__ float bf2f(ushort_t u) {
    unsigned x = ((unsigned)u) << 16;
    float f;
    __builtin_memcpy(&f, &x, 4);
    return f;
}
__device__ __forceinline__ ushort_t f2bf(float f) {
    unsigned x;
    __builtin_memcpy(&x, &f, 4);
    unsigned r = (x + 0x7FFF + ((x >> 16) & 1)) >> 16;   // RNE
    return (ushort_t)r;
}

// ---------------------------------------------------------------------------
// K1: coarse bucket histogram — LDS hist per block
__global__ void __launch_bounds__(512) bhist_kernel(const int* __restrict__ ei,
                                                    int* __restrict__ bhist,
                                                    int E, int NBUCK) {
    __shared__ int lh[512];
    lh[threadIdx.x] = 0;
    __syncthreads();
    int stride = gridDim.x * blockDim.x;
    for (int e = blockIdx.x * blockDim.x + threadIdx.x; e < E; e += stride)
        atomicAdd(&lh[ei[e] >> NBSH], 1);
    __syncthreads();
    if (threadIdx.x < NBUCK && lh[threadIdx.x])
        atomicAdd(&bhist[threadIdx.x], lh[threadIdx.x]);
}

// K2: exclusive scan of bucket counts -> bbase (sentinel), gcur
__global__ void __launch_bounds__(512) bscan_kernel(const int* __restrict__ bhist,
                                                    int* __restrict__ bbase,
                                                    int* __restrict__ gcur,
                                                    int NBUCK, int E) {
    __shared__ int s[512];
    int t = threadIdx.x;
    int v = (t < NBUCK) ? bhist[t] : 0;
    s[t] = v;
    __syncthreads();
    for (int o = 1; o < 512; o <<= 1) {
        int x = (t >= o) ? s[t - o] : 0;
        __syncthreads();
        s[t] += x;
        __syncthreads();
    }
    if (t < NBUCK) {
        int ex = s[t] - v;
        bbase[t] = ex;
        gcur[t] = ex;
    }
    if (t == 0) bbase[NBUCK] = E;
}

// K3: LDS-staged partition; entry = (local_dst<<17) | src  (local<256, src<2^17)
__global__ void __launch_bounds__(512) part1_kernel(const int* __restrict__ ei,
                                                    int* __restrict__ gcur,
                                                    int* __restrict__ part, int E) {
    __shared__ int stage[TILE];   // 32 KB
    __shared__ int lh[512];       // hist -> cursor
    __shared__ int sc[512];
    __shared__ int lofs[513];
    __shared__ int gbase[512];
    int t = threadIdx.x;
    int e0 = blockIdx.x * TILE;
    int cnt_tile = min(TILE, E - e0);
    lh[t] = 0;
    __syncthreads();
    for (int i = t; i < cnt_tile; i += PT)
        atomicAdd(&lh[ei[e0 + i] >> NBSH], 1);
    __syncthreads();
    sc[t] = lh[t];
    __syncthreads();
    for (int o = 1; o < 512; o <<= 1) {
        int v = (t >= o) ? sc[t - o] : 0;
        __syncthreads();
        sc[t] += v;
        __syncthreads();
    }
    {
        int cb = lh[t];
        int ex = sc[t] - cb;
        lofs[t] = ex;
        gbase[t] = cb ? atomicAdd(&gcur[t], cb) : 0;
        lh[t] = ex;   // LDS cursor
    }
    if (t == 0) lofs[512] = cnt_tile;
    __syncthreads();
    for (int i = t; i < cnt_tile; i += PT) {
        int dst = ei[e0 + i];
        int src = ei[E + e0 + i];
        int b = dst >> NBSH;
        int p = atomicAdd(&lh[b], 1);
        stage[p] = ((dst & (BKN - 1)) << 17) | src;
    }
    __syncthreads();
    for (int i = t; i < cnt_tile; i += PT) {   // coalesced copy-out
        int lo = 0, hi = 511;
        while (lo < hi) {
            int mid = (lo + hi + 1) >> 1;
            if (lofs[mid] <= i) lo = mid; else hi = mid - 1;
        }
        part[gbase[lo] + (i - lofs[lo])] = stage[i];
    }
}

// K4: per-bucket CSR build (256 nodes/block): hist -> scan -> rowst/dinv -> scatter
__global__ void __launch_bounds__(256) csr_kernel(const int* __restrict__ part,
                                                  const int* __restrict__ bbase,
                                                  int* __restrict__ csr,
                                                  int* __restrict__ rowst,
                                                  float* __restrict__ dinv,
                                                  int NBUCK, int N, int E) {
    __shared__ int h[256];
    __shared__ int cur[256];
    int b = blockIdx.x, t = threadIdx.x;
    int st = bbase[b], en = bbase[b + 1];
    h[t] = 0;
    __syncthreads();
    for (int e = st + t; e < en; e += 256)
        atomicAdd(&h[part[e] >> 17], 1);
    __syncthreads();
    int myc = h[t];
    for (int o = 1; o < 256; o <<= 1) {
        int v = (t >= o) ? h[t - o] : 0;
        __syncthreads();
        h[t] += v;
        __syncthreads();
    }
    int ex = h[t] - myc;
    int node = (b << NBSH) + t;
    if (node < N) {
        rowst[node] = st + ex;
        dinv[node] = rsqrtf((float)myc + 1.0f);
    }
    if (b == NBUCK - 1 && t == 0) rowst[N] = E;
    cur[t] = ex;
    __syncthreads();
    for (int e = st + t; e < en; e += 256) {
        int ent = part[e];
        int p = atomicAdd(&cur[ent >> 17], 1);
        csr[st + p] = ent & 0x1FFFF;
    }
}

// K5: h1s(bf16, stride 32) = dinv[row] * (x @ W1); W1 in LDS
__global__ void __launch_bounds__(256) gemm1_kernel(const float* __restrict__ x,
                                                    const float* __restrict__ W1,
                                                    const float* __restrict__ dinv,
                                                    unsigned* __restrict__ h1u, int N) {
    __shared__ float w[NFEAT * NHID];
    for (int i = threadIdx.x; i < NFEAT * NHID; i += blockDim.x) w[i] = W1[i];
    __syncthreads();
    int row = blockIdx.x * blockDim.x + threadIdx.x;
    if (row >= N) return;
    float acc[NHID];
#pragma unroll
    for (int j = 0; j < NHID; j++) acc[j] = 0.0f;
    const float4* xr = (const float4*)(x + (size_t)row * NFEAT);
    for (int k4 = 0; k4 < NFEAT / 4; k4++) {
        float4 v = xr[k4];
        const float* wr = &w[k4 * 4 * NHID];
#pragma unroll
        for (int j = 0; j < NHID; j++) acc[j] += v.x * wr[j];
#pragma unroll
        for (int j = 0; j < NHID; j++) acc[j] += v.y * wr[NHID + j];
#pragma unroll
        for (int j = 0; j < NHID; j++) acc[j] += v.z * wr[2 * NHID + j];
#pragma unroll
        for (int j = 0; j < NHID; j++) acc[j] += v.w * wr[3 * NHID + j];
    }
    float di = dinv[row];
    unsigned* o = h1u + (size_t)row * (H1STR / 2);
#pragma unroll
    for (int q = 0; q < NHID / 2; q++)
        o[q] = (unsigned)f2bf(di * acc[2 * q]) | ((unsigned)f2bf(di * acc[2 * q + 1]) << 16);
}

// K6: layer-1 pull aggregation (bf16 gathers) + self-loop/bias/relu -> hrelu fp32
__global__ void __launch_bounds__(192) agg1_kernel(const int* __restrict__ csr,
                                                   const int* __restrict__ rowst,
                                                   const ushort_t* __restrict__ h1sb,
                                                   const float* __restrict__ dinv,
                                                   const float* __restrict__ b1,
                                                   float* __restrict__ hrelu, int N) {
    int g = threadIdx.x / NHID;
    int f = threadIdx.x - g * NHID;
    int node = blockIdx.x * 8 + g;
    if (node >= N) return;
    int st = rowst[node];
    int dg = rowst[node + 1] - st;
    float a0 = 0.f, a1 = 0.f, a2 = 0.f, a3 = 0.f;
    int e = 0;
    for (; e + 4 <= dg; e += 4) {
        int s0 = csr[st + e];
        int s1 = csr[st + e + 1];
        int s2 = csr[st + e + 2];
        int s3 = csr[st + e + 3];
        a0 += bf2f(h1sb[s0 * H1STR + f]);
        a1 += bf2f(h1sb[s1 * H1STR + f]);
        a2 += bf2f(h1sb[s2 * H1STR + f]);
        a3 += bf2f(h1sb[s3 * H1STR + f]);
    }
    for (; e < dg; e++) a0 += bf2f(h1sb[csr[st + e] * H1STR + f]);
    float sum = (a0 + a1) + (a2 + a3);
    float v = dinv[node] * (sum + bf2f(h1sb[node * H1STR + f])) + b1[f];
    hrelu[node * NHID + f] = fmaxf(v, 0.0f);
}

// K7: h2s(bf16, stride 16) = dinv[row] * (hrelu @ W2)
__global__ void __launch_bounds__(256) fuse2_kernel(const float* __restrict__ hrelu,
                                                    const float* __restrict__ dinv,
                                                    const float* __restrict__ W2,
                                                    unsigned* __restrict__ h2u, int N) {
    __shared__ float w[NHID * NCLS];
    for (int i = threadIdx.x; i < NHID * NCLS; i += blockDim.x) w[i] = W2[i];
    __syncthreads();
    int row = blockIdx.x * blockDim.x + threadIdx.x;
    if (row >= N) return;
    float hr[NHID];
    const float4* h4 = (const float4*)(hrelu + (size_t)row * NHID);
#pragma unroll
    for (int q = 0; q < NHID / 4; q++) {
        float4 hv = h4[q];
        hr[4 * q + 0] = hv.x;
        hr[4 * q + 1] = hv.y;
        hr[4 * q + 2] = hv.z;
        hr[4 * q + 3] = hv.w;
    }
    float acc[NCLS];
#pragma unroll
    for (int j = 0; j < NCLS; j++) acc[j] = 0.0f;
#pragma unroll
    for (int k = 0; k < NHID; k++) {
#pragma unroll
        for (int j = 0; j < NCLS; j++) acc[j] += hr[k] * w[k * NCLS + j];
    }
    float di = dinv[row];
    unsigned* o = h2u + (size_t)row * (NCLS / 2);
#pragma unroll
    for (int q = 0; q < NCLS / 2; q++)
        o[q] = (unsigned)f2bf(di * acc[2 * q]) | ((unsigned)f2bf(di * acc[2 * q + 1]) << 16);
}

// K8: layer-2 pull aggregation (bf16 gathers) + self-loop + b2 + log_softmax
__global__ void __launch_bounds__(256) agg2_kernel(const int* __restrict__ csr,
                                                   const int* __restrict__ rowst,
                                                   const ushort_t* __restrict__ h2sb,
                                                   const float* __restrict__ dinv,
                                                   const float* __restrict__ b2,
                                                   float* __restrict__ out, int N) {
    int g = threadIdx.x >> 4;
    int f = threadIdx.x & 15;
    int node = blockIdx.x * 16 + g;
    if (node >= N) return;
    int st = rowst[node];
    int dg = rowst[node + 1] - st;
    float a0 = 0.f, a1 = 0.f, a2 = 0.f, a3 = 0.f;
    int e = 0;
    for (; e + 4 <= dg; e += 4) {
        int s0 = csr[st + e];
        int s1 = csr[st + e + 1];
        int s2 = csr[st + e + 2];
        int s3 = csr[st + e + 3];
        a0 += bf2f(h2sb[s0 * NCLS + f]);
        a1 += bf2f(h2sb[s1 * NCLS + f]);
        a2 += bf2f(h2sb[s2 * NCLS + f]);
        a3 += bf2f(h2sb[s3 * NCLS + f]);
    }
    for (; e < dg; e++) a0 += bf2f(h2sb[csr[st + e] * NCLS + f]);
    float sum = (a0 + a1) + (a2 + a3);
    float l = dinv[node] * (sum + bf2f(h2sb[node * NCLS + f])) + b2[f];
    float m = l;
#pragma unroll
    for (int o = 1; o < 16; o <<= 1) m = fmaxf(m, __shfl_xor(m, o, 16));
    float ex = expf(l - m);
    float ssum = ex;
#pragma unroll
    for (int o = 1; o < 16; o <<= 1) ssum += __shfl_xor(ssum, o, 16);
    out[node * NCLS + f] = l - (logf(ssum) + m);
}

extern "C" void kernel_launch(void* const* d_in, const int* in_sizes, int n_in,
                              void* d_out, int out_size, void* d_ws, size_t ws_size,
                              hipStream_t stream) {
    const float* x  = (const float*)d_in[0];
    const int*   ei = (const int*)d_in[1];
    const float* W1 = (const float*)d_in[2];
    const float* b1 = (const float*)d_in[3];
    const float* W2 = (const float*)d_in[4];
    const float* b2 = (const float*)d_in[5];
    float* out = (float*)d_out;

    const int N = in_sizes[0] / NFEAT;        // 100000
    const int E = in_sizes[1] / 2;            // 3200000
    const int NBUCK = (N + BKN - 1) >> NBSH;  // 391

    // workspace layout (4 B units, then 64 B-aligned bf16 region):
    int* bhist = (int*)d_ws;
    int* bbase = bhist + 512;          // NBUCK+1 used
    int* gcur  = bbase + 513;
    int* rowst = gcur + 512;
    int* csr   = rowst + (N + 1);
    float* dinv = (float*)(csr + E);
    size_t off = (size_t)(512 + 513 + 512 + (N + 1) + E + N) * 4;
    off = (off + 63) & ~(size_t)63;
    ushort_t* h1sb = (ushort_t*)((char*)d_ws + off);          // N*32 bf16 = 6.4 MB
    ushort_t* h2sb = h1sb;                                     // alias, h1s dead after agg1
    size_t off2 = off + (size_t)N * H1STR * 2;
    off2 = (off2 + 63) & ~(size_t)63;
    int*   part  = (int*)((char*)d_ws + off2);                 // E ints = 12.8 MB
    float* hrelu = (float*)part;                               // alias, part dead after csr

    hipMemsetAsync(bhist, 0, 512 * sizeof(int), stream);

    bhist_kernel<<<512, PT, 0, stream>>>(ei, bhist, E, NBUCK);
    bscan_kernel<<<1, PT, 0, stream>>>(bhist, bbase, gcur, NBUCK, E);
    part1_kernel<<<(E + TILE - 1) / TILE, PT, 0, stream>>>(ei, gcur, part, E);
    csr_kernel<<<NBUCK, 256, 0, stream>>>(part, bbase, csr, rowst, dinv, NBUCK, N, E);
    gemm1_kernel<<<(N + 255) / 256, 256, 0, stream>>>(x, W1, dinv, (unsigned*)h1sb, N);
    agg1_kernel<<<(N + 7) / 8, 192, 0, stream>>>(csr, rowst, h1sb, dinv, b1, hrelu, N);
    fuse2_kernel<<<(N + 255) / 256, 256, 0, stream>>>(hrelu, dinv, W2, (unsigned*)h2sb, N);
    agg2_kernel<<<(N + 15) / 16, 256, 0, stream>>>(csr, rowst, h2sb, dinv, b2, out, N);
}